// Round 7
// baseline (168.786 us; speedup 1.0000x reference)
//
#include <hip/hip_runtime.h>

// MyConv: masked 3x3 conv, B=8, Cin=Cout=128, H=W=128, pad=1, stride=1.
// v10 = v9 (conflict-free setup, v5 conv) + two isolated levers:
//  (1) setup writes xp/wp NON-TEMPORALLY (and reads x nt): R6 showed setup's
//      dirty xp lines (34.6MB) flushing inside conv's window (conv WRITE_SIZE
//      65.7->81-84MB, dur 49.5->60.8). nt stores stream to HBM, no L2 debt;
//      conv's xp reads were HBM-sourced anyway (FETCH=43MB=full xp).
//  (2) conv XCD-ownership remap: b=bid&7 -> each XCD owns one batch
//      (xp/b = 4.33MB ~ 4MB L2); inner order (h0,mhalf) puts mhalf-partners
//      (same xp slabs) and h0-neighbors (2/4 shared slab rows) adjacent on
//      one XCD's L2. Conv structure otherwise byte-identical v5 (only
//      measured local optimum: v6 occ 57.6, v7 vmcnt 64.6, v8 no-LDS 83.6).

typedef __bf16 bf16x8 __attribute__((ext_vector_type(8)));
typedef unsigned short u16x8 __attribute__((ext_vector_type(8)));
typedef float f32x4 __attribute__((ext_vector_type(4)));

__device__ __forceinline__ unsigned short f2bf(float f) {
    unsigned int u = __float_as_uint(f);
    u += 0x7fffu + ((u >> 16) & 1u);   // round-to-nearest-even
    return (unsigned short)(u >> 16);
}

// ---- merged setup: cvt x (blocks 0..4159) + pack W (blocks 4160..4735) ----
__global__ void setup_all(const float* __restrict__ x, const float* __restrict__ wgt,
                          unsigned short* __restrict__ xp, unsigned short* __restrict__ wpp) {
    __shared__ float Lf[32 * 132];
    const int t   = threadIdx.x;
    const int bid = blockIdx.x;

    if (bid >= 4160) {   // ---- weight pack: wp[kh][cb][kw][m][ci32] ----
        const int e    = (bid - 4160) * 256 + t;
        const int j    = e & 31;               // k-slot within cb
        const int m    = (e >> 5) & 127;
        const int r    = e >> 12;
        const int kw   = r - (r / 3) * 3;
        const int cbkh = r / 3;
        const int cb   = cbkh & 3;
        const int kh   = cbkh >> 2;
        const int ci   = 4 * (j & 7) + (j >> 3);   // k-slot permutation (matches xp)
        __builtin_nontemporal_store(f2bf(wgt[((m * 128 + cb * 32 + ci) * 3 + kh) * 3 + kw]), &wpp[e]);
        return;
    }

    // ---- x fp32 [b][ci][h][w] -> bf16 xp slab [(b*4+cb)*130+hh2][r=130][ci32] ----
    const int hh2 = bid % 130;
    const int cb  = (bid / 130) & 3;
    const int b   = bid / 520;
    u16x8* slab = (u16x8*)(xp + (size_t)(((b * 4 + cb) * 130 + hh2)) * 4160);
    const u16x8 z = {0, 0, 0, 0, 0, 0, 0, 0};

    if (hh2 == 0 || hh2 == 129) {      // guard slab
        for (int k = t; k < 520; k += 256) __builtin_nontemporal_store(z, &slab[k]);
        return;
    }
    const int h = hh2 - 1;

    #pragma unroll
    for (int u = 0; u < 4; ++u) {
        const int f  = t + 256 * u;    // 0..1023
        const int ci = f >> 5;
        const int w4 = f & 31;
        const f32x4 v = __builtin_nontemporal_load(
            (const f32x4*)(x + (((b * 128 + cb * 32 + ci) * 128 + h) << 7) + (w4 << 2)));
        *(f32x4*)&Lf[ci * 132 + (w4 << 2)] = v;
    }
    __syncthreads();

    for (int k = t; k < 520; k += 256) {
        const int r = k >> 2;
        const int c = k & 3;
        u16x8 o;
        if (r == 0 || r == 129) {
            o = z;
        } else {
            const int w  = r - 1;
            const int lc = c ^ ((r + (r >> 2)) & 3);   // swizzled logical chunk
            // slot (lc,s) holds ci = 4s+lc: lanes sharing (w,s) have distinct
            // lc -> banks (16s + 4*lc + w) mod 32 distinct -> conflict-free
            #pragma unroll
            for (int s = 0; s < 8; ++s) o[s] = f2bf(Lf[(4 * s + lc) * 132 + w]);
        }
        __builtin_nontemporal_store(o, &slab[k]);
    }
}

__device__ __forceinline__ void stage_slabs(const unsigned char* gx, unsigned char* ls, int t) {
    const int g    = t >> 6;       // wave-uniform
    const int lane = t & 63;
    #pragma unroll
    for (int u = 0; u < 8; ++u)
        __builtin_amdgcn_global_load_lds(
            (const __attribute__((address_space(1))) unsigned int*)(gx + u * 2048 + g * 1024 + lane * 16),
            (__attribute__((address_space(3))) unsigned int*)(ls + u * 2048 + g * 1024),
            16, 0, 0);
    if (t < 16)   // 256B tail, lanes 0-15 of wave 0
        __builtin_amdgcn_global_load_lds(
            (const __attribute__((address_space(1))) unsigned int*)(gx + 16384 + t * 16),
            (__attribute__((address_space(3))) unsigned int*)(ls + 16384),
            16, 0, 0);
}

__global__ __launch_bounds__(128, 2)
void myconv5(const unsigned short* __restrict__ xp,
             const int* __restrict__ mask,
             const unsigned short* __restrict__ wp,
             const float* __restrict__ bias,
             float* __restrict__ out)
{
    __shared__ __align__(16) unsigned char Xs[2][16640];  // dbuf: 2 slabs each
    __shared__ float act[256];

    const int t = threadIdx.x;           // 0..127
    // XCD-ownership remap (bijective, 1024 = 8 XCD x 128): XCD = b; within
    // an XCD, consecutive blocks walk (h0, mhalf) -> mhalf partners and
    // h0-neighbors share xp slabs through the same L2.
    const int b     = blockIdx.x & 7;
    const int r8    = blockIdx.x >> 3;   // 0..127
    const int mhalf = r8 & 1;
    const int h0    = (r8 >> 1) << 1;

    const int lane = t & 63;
    const int l16  = lane & 15;
    const int q    = lane >> 4;
    const int g    = t >> 6;             // wave -> h row

    const unsigned char* xpB = (const unsigned char*)xp;

    // ---- stage round 0 immediately ----
    stage_slabs(xpB + (size_t)((b * 4 + 0) * 130 + h0 + 0) * 8320, &Xs[0][0], t);

    // ---- active map for rows h0, h0+1 (t = w) ----
    #pragma unroll
    for (int gg = 0; gg < 2; ++gg) {
        const int h = h0 + gg;
        int any = 0;
        #pragma unroll
        for (int kh = 0; kh < 3; ++kh) {
            int hh = h + kh - 1;
            if ((unsigned)hh < 128u) {
                const int* mrow = mask + (b * 128 + hh) * 128;
                #pragma unroll
                for (int kw = 0; kw < 3; ++kw) {
                    int ww = t + kw - 1;
                    if ((unsigned)ww < 128u) any |= mrow[ww];
                }
            }
        }
        act[gg * 128 + t] = any ? 1.0f : 0.0f;
    }

    // B fragment byte offsets (per kw, j-independent swizzle)
    int bb[3];
    #pragma unroll
    for (int kw = 0; kw < 3; ++kw) {
        const int rr   = l16 + kw;
        const int slot = q ^ ((rr + (rr >> 2)) & 3);
        bb[kw] = g * 8320 + rr * 64 + (slot << 4);
    }

    const unsigned char* agl = (const unsigned char*)wp + (mhalf * 64 + l16) * 64 + q * 16;

    f32x4 acc[4][8];
    const f32x4 fzero = {0.f, 0.f, 0.f, 0.f};
    #pragma unroll
    for (int i = 0; i < 4; ++i)
        #pragma unroll
        for (int j = 0; j < 8; ++j)
            acc[i][j] = fzero;

    __syncthreads();   // round-0 staging + act complete

    for (int r = 0; r < 12; ++r) {
        // ---- prefetch round r+1 into the other buffer (no wait here) ----
        if (r < 11) {
            const int rn = r + 1;
            stage_slabs(xpB + (size_t)((b * 4 + (rn & 3)) * 130 + h0 + (rn >> 2)) * 8320,
                        &Xs[(rn & 1)][0], t);
        }

        const unsigned char* ar = agl + r * 24576;
        const unsigned char* xb = &Xs[r & 1][0];
        #pragma unroll
        for (int kw = 0; kw < 3; ++kw) {
            bf16x8 af[4];
            #pragma unroll
            for (int i = 0; i < 4; ++i)
                af[i] = *(const bf16x8*)(ar + kw * 8192 + i * 1024);
            bf16x8 bfr[8];
            #pragma unroll
            for (int j = 0; j < 8; ++j)
                bfr[j] = *(const bf16x8*)(xb + bb[kw] + j * 1024);
            #pragma unroll
            for (int i = 0; i < 4; ++i)
                #pragma unroll
                for (int j = 0; j < 8; ++j)
                    acc[i][j] = __builtin_amdgcn_mfma_f32_16x16x32_bf16(af[i], bfr[j], acc[i][j], 0, 0, 0);
        }

        __syncthreads();   // drains r+1 staging (overlapped with compute above)
    }

    // ---- epilogue: (acc + bias) * active ----
    #pragma unroll
    for (int i = 0; i < 4; ++i) {
        const int m0 = mhalf * 64 + (i << 4) + (q << 2);
        const f32x4 bv = *(const f32x4*)(bias + m0);
        #pragma unroll
        for (int j = 0; j < 8; ++j) {
            const int w = (j << 4) + l16;
            const float a = act[(g << 7) + w];
            float* base = out + (((b << 7) + m0) << 14) + ((h0 + g) << 7) + w;
            #pragma unroll
            for (int rg = 0; rg < 4; ++rg)
                base[rg << 14] = (acc[i][j][rg] + bv[rg]) * a;
        }
    }
}

// ---------------- Round-1 fallback (used only if ws too small) ----------------
#define LDAF 40
__global__ __launch_bounds__(256, 2)
void myconv_fb(const float* __restrict__ x,
               const int* __restrict__ mask,
               const float* __restrict__ wgt,
               const float* __restrict__ bias,
               float* __restrict__ out)
{
    __shared__ unsigned short As[128 * LDAF];
    __shared__ unsigned short Bs[128 * LDAF];
    __shared__ float act[128];

    const int t   = threadIdx.x;
    const int blk = blockIdx.x;
    const int b   = blk >> 7;
    const int h   = blk & 127;

    if (t < 128) {
        int any = 0;
        #pragma unroll
        for (int kh = 0; kh < 3; ++kh) {
            int hh = h + kh - 1;
            if ((unsigned)hh < 128u) {
                const int* mrow = mask + (b * 128 + hh) * 128;
                #pragma unroll
                for (int kw = 0; kw < 3; ++kw) {
                    int ww = t + kw - 1;
                    if ((unsigned)ww < 128u) any |= mrow[ww];
                }
            }
        }
        act[t] = any ? 1.0f : 0.0f;
    }

    const int lane = t & 63;
    const int l16  = lane & 15;
    const int half = lane >> 4;
    const int wv   = t >> 6;
    const int wm   = (wv >> 1) << 6;
    const int wn   = (wv & 1) << 6;

    f32x4 acc[4][4];
    const f32x4 fzero = {0.f, 0.f, 0.f, 0.f};
    #pragma unroll
    for (int i = 0; i < 4; ++i)
        #pragma unroll
        for (int j = 0; j < 4; ++j)
            acc[i][j] = fzero;

    const int am  = t >> 3;
    const int ac4 = (t & 7) << 2;
    const int n     = t & 127;
    const int khalf = __builtin_amdgcn_readfirstlane(t >> 7);
    const int xb    = b << 21;

    for (int kt = 0; kt < 36; ++kt) {
        __syncthreads();
        #pragma unroll
        for (int jj = 0; jj < 4; ++jj) {
            const int m = am + (jj << 5);
            const float4 v = *(const float4*)(wgt + m * 1152 + kt * 32 + ac4);
            unsigned short* dst = &As[m * LDAF + ac4];
            dst[0] = f2bf(v.x); dst[1] = f2bf(v.y); dst[2] = f2bf(v.z); dst[3] = f2bf(v.w);
        }
        u16x8 bv0, bv1;
        #pragma unroll
        for (int s = 0; s < 16; ++s) {
            const int k  = kt * 32 + khalf * 16 + s;
            const int ci = (k * 7282) >> 16;
            const int r  = k - ci * 9;
            const int kh = (r >= 3) + (r >= 6);
            const int kw = r - kh * 3;
            const int hh = h + kh - 1;
            float v = 0.f;
            if ((unsigned)hh < 128u) {
                const int ww = n + kw - 1;
                if ((unsigned)ww < 128u)
                    v = x[xb + (ci << 14) + (hh << 7) + ww];
            }
            if (s < 8) bv0[s] = f2bf(v); else bv1[s - 8] = f2bf(v);
        }
        *(u16x8*)&Bs[n * LDAF + khalf * 16]     = bv0;
        *(u16x8*)&Bs[n * LDAF + khalf * 16 + 8] = bv1;

        __syncthreads();

        bf16x8 af[4], bfr[4];
        #pragma unroll
        for (int i = 0; i < 4; ++i)
            af[i] = *(const bf16x8*)&As[(wm + (i << 4) + l16) * LDAF + (half << 3)];
        #pragma unroll
        for (int j = 0; j < 4; ++j)
            bfr[j] = *(const bf16x8*)&Bs[(wn + (j << 4) + l16) * LDAF + (half << 3)];
        #pragma unroll
        for (int i = 0; i < 4; ++i)
            #pragma unroll
            for (int j = 0; j < 4; ++j)
                acc[i][j] = __builtin_amdgcn_mfma_f32_16x16x32_bf16(af[i], bfr[j], acc[i][j], 0, 0, 0);
    }

    #pragma unroll
    for (int i = 0; i < 4; ++i) {
        #pragma unroll
        for (int j = 0; j < 4; ++j) {
            const int ncol = wn + (j << 4) + l16;
            const float a  = act[ncol];
            #pragma unroll
            for (int rg = 0; rg < 4; ++rg) {
                const int m = wm + (i << 4) + (half << 2) + rg;
                out[(((b << 7) + m) << 14) + (h << 7) + ncol] =
                    (acc[i][j][rg] + bias[m]) * a;
            }
        }
    }
}

extern "C" void kernel_launch(void* const* d_in, const int* in_sizes, int n_in,
                              void* d_out, int out_size, void* d_ws, size_t ws_size,
                              hipStream_t stream) {
    const float* x    = (const float*)d_in[0];
    const int*   mask = (const int*)d_in[1];
    const float* wgt  = (const float*)d_in[2];
    const float* bias = (const float*)d_in[3];
    float* out        = (float*)d_out;

    const size_t XP_ELEMS = 4160ull * 4160;   // 17,305,600 bf16 (8*4*130 slabs)
    const size_t WP_ELEMS = 36ull * 128 * 32; //    147,456 bf16
    const size_t need = (XP_ELEMS + WP_ELEMS) * 2;

    if (ws_size >= need) {
        unsigned short* xpw = (unsigned short*)d_ws;
        unsigned short* wpw = xpw + XP_ELEMS;
        setup_all<<<dim3(4736), dim3(256), 0, stream>>>(x, wgt, xpw, wpw);
        myconv5<<<dim3(1024), dim3(128), 0, stream>>>(xpw, mask, wpw, bias, out);
    } else {
        myconv_fb<<<dim3(1024), dim3(256), 0, stream>>>(x, mask, wgt, bias, out);
    }
}

// Round 8
// 162.632 us; speedup vs baseline: 1.0378x; 1.0378x over previous
//
#include <hip/hip_runtime.h>

// MyConv: masked 3x3 conv, B=8, Cin=Cout=128, H=W=128, pad=1, stride=1.
// v11: FUSED. Decomposition over R0-R7: total = conv(50-58) + setup(35-50)
// + fixed harness ~55us. Conv is a measured local optimum (v6 occ 57.6,
// v7 vmcnt 64.6, v8 no-LDS 83.6 all regressed); setup is invisible to
// top-5 profiling and its xp roundtrip costs ~70MB HBM + L2 interference.
// v11 deletes setup_all: the conv kernel converts x fp32->bf16 on the fly
// while staging. Inner MFMA loop / LDS layout / barriers / epilogue are
// BYTE-IDENTICAL to v5. stage_slabs (global_load_lds from xp) is replaced
// by stage_conv: per thread 8 chunks, each = 8 coalesced fp32 loads
// (lanes=consecutive w, 256B/instr), f2bf, ONE ds_write_b128 to the same
// swizzled slot (ds_write scatters per-lane; the swizzle global_load_lds
// couldn't express is free here). Guard rows (rr=0,129) zeroed once in
// prologue; h-guard rows zeroed by uniform branch. Slot->ci permutation
// ci=4s+lc matches wp pack ci=4*(j&7)+(j>>3) (R6 scheme, A/B agree).
// wp pack survives as a 576-block ~2us kernel. R7's XCD remap kept
// (FETCH -9MB measured). ws need drops to 2*WP bytes.

typedef __bf16 bf16x8 __attribute__((ext_vector_type(8)));
typedef unsigned short u16x8 __attribute__((ext_vector_type(8)));
typedef float f32x4 __attribute__((ext_vector_type(4)));

__device__ __forceinline__ unsigned short f2bf(float f) {
    unsigned int u = __float_as_uint(f);
    u += 0x7fffu + ((u >> 16) & 1u);   // round-to-nearest-even
    return (unsigned short)(u >> 16);
}

// ---- weight pack: wp[kh][cb][kw][m][ci32], k-slot perm ci=4*(j&7)+(j>>3) ----
__global__ void setup_wp(const float* __restrict__ wgt, unsigned short* __restrict__ wpp) {
    const int e    = blockIdx.x * 256 + threadIdx.x;   // 576*256 = 147456
    const int j    = e & 31;
    const int m    = (e >> 5) & 127;
    const int r    = e >> 12;
    const int kw   = r - (r / 3) * 3;
    const int cbkh = r / 3;
    const int cb   = cbkh & 3;
    const int kh   = cbkh >> 2;
    const int ci   = 4 * (j & 7) + (j >> 3);
    wpp[e] = f2bf(wgt[((m * 128 + cb * 32 + ci) * 3 + kh) * 3 + kw]);
}

// ---- fused staging: convert 2 slab rows (x fp32 -> bf16) into Xs buffer ----
// thread t owns w-row rr=t+1; per (y,lc): 8 coalesced loads + 1 ds_write_b128.
__device__ __forceinline__ void stage_conv(const float* __restrict__ x,
                                           unsigned char* XsN,
                                           int b, int cb, int hb, int t) {
    const u16x8 z  = {0, 0, 0, 0, 0, 0, 0, 0};
    const int rr   = t + 1;                       // 1..128
    const int cswz = (rr + (rr >> 2)) & 3;
    #pragma unroll
    for (int y = 0; y < 2; ++y) {
        const int h    = hb + y;
        const bool inb = (unsigned)h < 128u;      // block-uniform
        const float* xr = x + ((((b * 128 + cb * 32) * 128) + h) << 7) + t;
        #pragma unroll
        for (int lc = 0; lc < 4; ++lc) {
            u16x8 o = z;
            if (inb) {
                #pragma unroll
                for (int s = 0; s < 8; ++s)       // ci = cb*32 + 4s + lc
                    o[s] = f2bf(xr[(lc << 14) + (s << 16)]);
            }
            *(u16x8*)(XsN + y * 8320 + rr * 64 + ((lc ^ cswz) << 4)) = o;
        }
    }
}

__global__ __launch_bounds__(128, 2)
void myconv11(const float* __restrict__ x,
              const int* __restrict__ mask,
              const unsigned short* __restrict__ wp,
              const float* __restrict__ bias,
              float* __restrict__ out)
{
    __shared__ __align__(16) unsigned char Xs[2][16640];  // dbuf: 2 slab rows each
    __shared__ float act[256];

    const int t = threadIdx.x;           // 0..127
    // XCD remap (R7, measured FETCH -9MB): XCD = batch; inner (h0,mhalf)
    // keeps slab-sharing neighbors temporally adjacent on one L2.
    const int b     = blockIdx.x & 7;
    const int r8    = blockIdx.x >> 3;   // 0..127
    const int mhalf = r8 & 1;
    const int h0    = (r8 >> 1) << 1;

    const int lane = t & 63;
    const int l16  = lane & 15;
    const int q    = lane >> 4;
    const int g    = t >> 6;             // wave -> h row

    // ---- prologue: zero w-guard rows (rr=0,129) of BOTH buffers, once ----
    if (t < 32) {
        const u16x8 z = {0, 0, 0, 0, 0, 0, 0, 0};
        const int bf = (t >> 4) & 1;
        const int y  = (t >> 3) & 1;
        const int rr = ((t >> 2) & 1) ? 129 : 0;
        const int c  = t & 3;
        *(u16x8*)(&Xs[bf][0] + y * 8320 + rr * 64 + (c << 4)) = z;
    }

    // ---- stage round 0 (cb=0, hb=h0-1) ----
    stage_conv(x, &Xs[0][0], b, 0, h0 - 1, t);

    // ---- active map for rows h0, h0+1 (t = w) ----
    #pragma unroll
    for (int gg = 0; gg < 2; ++gg) {
        const int h = h0 + gg;
        int any = 0;
        #pragma unroll
        for (int kh = 0; kh < 3; ++kh) {
            int hh = h + kh - 1;
            if ((unsigned)hh < 128u) {
                const int* mrow = mask + (b * 128 + hh) * 128;
                #pragma unroll
                for (int kw = 0; kw < 3; ++kw) {
                    int ww = t + kw - 1;
                    if ((unsigned)ww < 128u) any |= mrow[ww];
                }
            }
        }
        act[gg * 128 + t] = any ? 1.0f : 0.0f;
    }

    // B fragment byte offsets (per kw, j-independent swizzle) — identical v5
    int bb[3];
    #pragma unroll
    for (int kw = 0; kw < 3; ++kw) {
        const int rr   = l16 + kw;
        const int slot = q ^ ((rr + (rr >> 2)) & 3);
        bb[kw] = g * 8320 + rr * 64 + (slot << 4);
    }

    const unsigned char* agl = (const unsigned char*)wp + (mhalf * 64 + l16) * 64 + q * 16;

    f32x4 acc[4][8];
    const f32x4 fzero = {0.f, 0.f, 0.f, 0.f};
    #pragma unroll
    for (int i = 0; i < 4; ++i)
        #pragma unroll
        for (int j = 0; j < 8; ++j)
            acc[i][j] = fzero;

    __syncthreads();   // round-0 staging + guards + act complete

    for (int r = 0; r < 12; ++r) {       // r = kh*4 + cb
        // ---- stage round r+1 into the other buffer (overlaps compute) ----
        if (r < 11) {
            const int rn = r + 1;
            stage_conv(x, &Xs[rn & 1][0], b, rn & 3, h0 + (rn >> 2) - 1, t);
        }

        const unsigned char* ar = agl + r * 24576;
        const unsigned char* xb = &Xs[r & 1][0];
        #pragma unroll
        for (int kw = 0; kw < 3; ++kw) {
            bf16x8 af[4];
            #pragma unroll
            for (int i = 0; i < 4; ++i)
                af[i] = *(const bf16x8*)(ar + kw * 8192 + i * 1024);
            bf16x8 bfr[8];
            #pragma unroll
            for (int j = 0; j < 8; ++j)
                bfr[j] = *(const bf16x8*)(xb + bb[kw] + j * 1024);
            #pragma unroll
            for (int i = 0; i < 4; ++i)
                #pragma unroll
                for (int j = 0; j < 8; ++j)
                    acc[i][j] = __builtin_amdgcn_mfma_f32_16x16x32_bf16(af[i], bfr[j], acc[i][j], 0, 0, 0);
        }

        __syncthreads();   // staging writes of r+1 visible; read-buffer reusable
    }

    // ---- epilogue: (acc + bias) * active ----
    #pragma unroll
    for (int i = 0; i < 4; ++i) {
        const int m0 = mhalf * 64 + (i << 4) + (q << 2);
        const f32x4 bv = *(const f32x4*)(bias + m0);
        #pragma unroll
        for (int j = 0; j < 8; ++j) {
            const int w = (j << 4) + l16;
            const float a = act[(g << 7) + w];
            float* base = out + (((b << 7) + m0) << 14) + ((h0 + g) << 7) + w;
            #pragma unroll
            for (int rg = 0; rg < 4; ++rg)
                base[rg << 14] = (acc[i][j][rg] + bv[rg]) * a;
        }
    }
}

// ---------------- fallback (used only if ws too small) ----------------
#define LDAF 40
__global__ __launch_bounds__(256, 2)
void myconv_fb(const float* __restrict__ x,
               const int* __restrict__ mask,
               const float* __restrict__ wgt,
               const float* __restrict__ bias,
               float* __restrict__ out)
{
    __shared__ unsigned short As[128 * LDAF];
    __shared__ unsigned short Bs[128 * LDAF];
    __shared__ float act[128];

    const int t   = threadIdx.x;
    const int blk = blockIdx.x;
    const int b   = blk >> 7;
    const int h   = blk & 127;

    if (t < 128) {
        int any = 0;
        #pragma unroll
        for (int kh = 0; kh < 3; ++kh) {
            int hh = h + kh - 1;
            if ((unsigned)hh < 128u) {
                const int* mrow = mask + (b * 128 + hh) * 128;
                #pragma unroll
                for (int kw = 0; kw < 3; ++kw) {
                    int ww = t + kw - 1;
                    if ((unsigned)ww < 128u) any |= mrow[ww];
                }
            }
        }
        act[t] = any ? 1.0f : 0.0f;
    }

    const int lane = t & 63;
    const int l16  = lane & 15;
    const int half = lane >> 4;
    const int wv   = t >> 6;
    const int wm   = (wv >> 1) << 6;
    const int wn   = (wv & 1) << 6;

    f32x4 acc[4][4];
    const f32x4 fzero = {0.f, 0.f, 0.f, 0.f};
    #pragma unroll
    for (int i = 0; i < 4; ++i)
        #pragma unroll
        for (int j = 0; j < 4; ++j)
            acc[i][j] = fzero;

    const int am  = t >> 3;
    const int ac4 = (t & 7) << 2;
    const int n     = t & 127;
    const int khalf = __builtin_amdgcn_readfirstlane(t >> 7);
    const int xb    = b << 21;

    for (int kt = 0; kt < 36; ++kt) {
        __syncthreads();
        #pragma unroll
        for (int jj = 0; jj < 4; ++jj) {
            const int m = am + (jj << 5);
            const float4 v = *(const float4*)(wgt + m * 1152 + kt * 32 + ac4);
            unsigned short* dst = &As[m * LDAF + ac4];
            dst[0] = f2bf(v.x); dst[1] = f2bf(v.y); dst[2] = f2bf(v.z); dst[3] = f2bf(v.w);
        }
        u16x8 bv0, bv1;
        #pragma unroll
        for (int s = 0; s < 16; ++s) {
            const int k  = kt * 32 + khalf * 16 + s;
            const int ci = (k * 7282) >> 16;
            const int r  = k - ci * 9;
            const int kh = (r >= 3) + (r >= 6);
            const int kw = r - kh * 3;
            const int hh = h + kh - 1;
            float v = 0.f;
            if ((unsigned)hh < 128u) {
                const int ww = n + kw - 1;
                if ((unsigned)ww < 128u)
                    v = x[xb + (ci << 14) + (hh << 7) + ww];
            }
            if (s < 8) bv0[s] = f2bf(v); else bv1[s - 8] = f2bf(v);
        }
        *(u16x8*)&Bs[n * LDAF + khalf * 16]     = bv0;
        *(u16x8*)&Bs[n * LDAF + khalf * 16 + 8] = bv1;

        __syncthreads();

        bf16x8 af[4], bfr[4];
        #pragma unroll
        for (int i = 0; i < 4; ++i)
            af[i] = *(const bf16x8*)&As[(wm + (i << 4) + l16) * LDAF + (half << 3)];
        #pragma unroll
        for (int j = 0; j < 4; ++j)
            bfr[j] = *(const bf16x8*)&Bs[(wn + (j << 4) + l16) * LDAF + (half << 3)];
        #pragma unroll
        for (int i = 0; i < 4; ++i)
            #pragma unroll
            for (int j = 0; j < 4; ++j)
                acc[i][j] = __builtin_amdgcn_mfma_f32_16x16x32_bf16(af[i], bfr[j], acc[i][j], 0, 0, 0);
    }

    #pragma unroll
    for (int i = 0; i < 4; ++i) {
        #pragma unroll
        for (int j = 0; j < 4; ++j) {
            const int ncol = wn + (j << 4) + l16;
            const float a  = act[ncol];
            #pragma unroll
            for (int rg = 0; rg < 4; ++rg) {
                const int m = wm + (i << 4) + (half << 2) + rg;
                out[(((b << 7) + m) << 14) + (h << 7) + ncol] =
                    (acc[i][j][rg] + bias[m]) * a;
            }
        }
    }
}

extern "C" void kernel_launch(void* const* d_in, const int* in_sizes, int n_in,
                              void* d_out, int out_size, void* d_ws, size_t ws_size,
                              hipStream_t stream) {
    const float* x    = (const float*)d_in[0];
    const int*   mask = (const int*)d_in[1];
    const float* wgt  = (const float*)d_in[2];
    const float* bias = (const float*)d_in[3];
    float* out        = (float*)d_out;

    const size_t WP_ELEMS = 36ull * 128 * 32;   // 147,456 bf16
    if (ws_size >= WP_ELEMS * 2) {
        unsigned short* wpw = (unsigned short*)d_ws;
        setup_wp<<<dim3(576), dim3(256), 0, stream>>>(wgt, wpw);
        myconv11<<<dim3(1024), dim3(128), 0, stream>>>(x, mask, wpw, bias, out);
    } else {
        myconv_fb<<<dim3(1024), dim3(256), 0, stream>>>(x, mask, wgt, bias, out);
    }
}

// Round 9
// 139.931 us; speedup vs baseline: 1.2062x; 1.1622x over previous
//
#include <hip/hip_runtime.h>

// MyConv: masked 3x3 conv, B=8, Cin=Cout=128, H=W=128, pad=1, stride=1.
// v12: fused (v11) minus the measured redundancy. v11 counters: conv 82us,
// FETCH 100MB (6x logical x re-read), VALUBusy 20% (768 ld+cvt/thread),
// +1.57M ds_write bank-conflict cycles; rest-time dropped 102->80.6 (fusion
// direction confirmed). v12:
//  (1) mhalf merged: 256-thr/4-wave block (mhalf=t>>7, g=(t>>6)&1), grid
//      512 -> staging + x-fetch per output halved.
//  (2) row-dedup: LDS holds the 4 distinct padded rows h0-1..h0+2 of the
//      current cb in 4 fixed slab positions; wave g at kh reads slab kh+g.
//      16 slab-stages/block (vs v11-equiv 24 at 2x grid) -> 3x less
//      conversion VALU, logical x 402->134MB.
//  (3) in-place interleaved staging, NO double buffer (LDS 34.3KB):
//      I0 stages pos2,3 while kh0 reads 0,1; I1 stages pos0 (cb+1.s0)
//      while kh1 reads 1,2; I2 stages pos1 while kh2 reads 2,3. Every
//      stage->read pair separated by >=1 barrier; 12 barriers + prologue.
// Inner MFMA/kw loop, swizzle, wp layout, epilogue formulas = v5 verbatim.
// Slot->ci permutation ci=4s+lc matches setup_wp ci=4*(j&7)+(j>>3).

typedef __bf16 bf16x8 __attribute__((ext_vector_type(8)));
typedef unsigned short u16x8 __attribute__((ext_vector_type(8)));
typedef float f32x4 __attribute__((ext_vector_type(4)));

__device__ __forceinline__ unsigned short f2bf(float f) {
    unsigned int u = __float_as_uint(f);
    u += 0x7fffu + ((u >> 16) & 1u);   // round-to-nearest-even
    return (unsigned short)(u >> 16);
}

// ---- weight pack: wp[kh][cb][kw][m][ci32], k-slot perm ci=4*(j&7)+(j>>3) ----
__global__ void setup_wp(const float* __restrict__ wgt, unsigned short* __restrict__ wpp) {
    const int e    = blockIdx.x * 256 + threadIdx.x;   // 576*256 = 147456
    const int j    = e & 31;
    const int m    = (e >> 5) & 127;
    const int r    = e >> 12;
    const int kw   = r - (r / 3) * 3;
    const int cbkh = r / 3;
    const int cb   = cbkh & 3;
    const int kh   = cbkh >> 2;
    const int ci   = 4 * (j & 7) + (j >> 3);
    wpp[e] = f2bf(wgt[((m * 128 + cb * 32 + ci) * 3 + kh) * 3 + kw]);
}

// ---- stage ONE padded row (130 w-slots x 32ci) with 256 threads ----
// thread t: w-slot rr=(t&127)+1, lc pair (t>>7)*2..+1: 16 coalesced fp32
// loads + 2 ds_write_b128 to the swizzled slots (read swizzle = v5).
__device__ __forceinline__ void stage1(const float* __restrict__ x,
                                       unsigned char* slab,
                                       int b, int cb, int h, int t) {
    const int rr   = (t & 127) + 1;
    const int cswz = (rr + (rr >> 2)) & 3;
    const int lc0  = (t >> 7) << 1;
    const bool inb = (unsigned)h < 128u;          // wave-uniform
    const float* xr = x + ((((b * 128 + cb * 32) * 128) + h) << 7) + (rr - 1);
    #pragma unroll
    for (int d = 0; d < 2; ++d) {
        const int lc = lc0 + d;
        u16x8 o = {0, 0, 0, 0, 0, 0, 0, 0};
        if (inb) {
            #pragma unroll
            for (int s = 0; s < 8; ++s)           // ci = cb*32 + 4s + lc
                o[s] = f2bf(xr[(lc << 14) + (s << 16)]);
        }
        *(u16x8*)(slab + rr * 64 + ((lc ^ cswz) << 4)) = o;
    }
}

__global__ __launch_bounds__(256, 2)
void myconv12(const float* __restrict__ x,
              const int* __restrict__ mask,
              const unsigned short* __restrict__ wp,
              const float* __restrict__ bias,
              float* __restrict__ out)
{
    __shared__ __align__(16) unsigned char Xs[4 * 8320];  // 4 slab positions
    __shared__ float act[256];

    const int t = threadIdx.x;           // 0..255
    // XCD remap (R7: FETCH -9MB measured): XCD = batch; h0 ascending within.
    const int b  = blockIdx.x & 7;
    const int h0 = (blockIdx.x >> 3) << 1;   // 0..126

    const int lane  = t & 63;
    const int l16   = lane & 15;
    const int q     = lane >> 4;
    const int g     = (t >> 6) & 1;      // wave -> output h row
    const int mhalf = t >> 7;            // wave -> Cout half

    // ---- w-guard slots rr=0,129 of all 4 slabs, zeroed once ----
    if (t < 32) {
        const u16x8 z = {0, 0, 0, 0, 0, 0, 0, 0};
        const int p  = t >> 3;                     // slab 0..3
        const int rr = (t & 4) ? 129 : 0;
        const int c  = t & 3;
        *(u16x8*)(&Xs[p * 8320] + rr * 64 + (c << 4)) = z;
    }

    // ---- active map for rows h0, h0+1 (t = gg*128 + w) ----
    {
        const int gg = t >> 7;
        const int w  = t & 127;
        const int h  = h0 + gg;
        int any = 0;
        #pragma unroll
        for (int kh = 0; kh < 3; ++kh) {
            int hh = h + kh - 1;
            if ((unsigned)hh < 128u) {
                const int* mrow = mask + (b * 128 + hh) * 128;
                #pragma unroll
                for (int kw = 0; kw < 3; ++kw) {
                    int ww = w + kw - 1;
                    if ((unsigned)ww < 128u) any |= mrow[ww];
                }
            }
        }
        act[t] = any ? 1.0f : 0.0f;
    }

    // ---- prologue: stage cb=0's 4 rows into positions 0..3 ----
    #pragma unroll
    for (int y = 0; y < 4; ++y)
        stage1(x, &Xs[y * 8320], b, 0, h0 - 1 + y, t);

    // B fragment byte offsets (per kw, j-independent swizzle) — v5 verbatim
    int bb[3];
    #pragma unroll
    for (int kw = 0; kw < 3; ++kw) {
        const int rr   = l16 + kw;
        const int slot = q ^ ((rr + (rr >> 2)) & 3);
        bb[kw] = rr * 64 + (slot << 4);
    }

    const unsigned char* agl = (const unsigned char*)wp + (mhalf * 64 + l16) * 64 + q * 16;

    f32x4 acc[4][8];
    const f32x4 fzero = {0.f, 0.f, 0.f, 0.f};
    #pragma unroll
    for (int i = 0; i < 4; ++i)
        #pragma unroll
        for (int j = 0; j < 8; ++j)
            acc[i][j] = fzero;

    __syncthreads();   // prologue staging + guards + act complete

#define COMPUTE_KH(k)                                                          \
    {                                                                          \
        const unsigned char* ar = agl + ((k) * 4 + cb) * 24576;                \
        const unsigned char* xb = &Xs[((k) + g) * 8320];                       \
        _Pragma("unroll")                                                      \
        for (int kw = 0; kw < 3; ++kw) {                                       \
            bf16x8 af[4];                                                      \
            _Pragma("unroll")                                                  \
            for (int i = 0; i < 4; ++i)                                        \
                af[i] = *(const bf16x8*)(ar + kw * 8192 + i * 1024);           \
            bf16x8 bfr[8];                                                     \
            _Pragma("unroll")                                                  \
            for (int j = 0; j < 8; ++j)                                        \
                bfr[j] = *(const bf16x8*)(xb + bb[kw] + j * 1024);             \
            _Pragma("unroll")                                                  \
            for (int i = 0; i < 4; ++i)                                        \
                _Pragma("unroll")                                              \
                for (int j = 0; j < 8; ++j)                                    \
                    acc[i][j] = __builtin_amdgcn_mfma_f32_16x16x32_bf16(       \
                        af[i], bfr[j], acc[i][j], 0, 0, 0);                    \
        }                                                                      \
    }

    for (int cb = 0; cb < 4; ++cb) {
        // I0: stage THIS cb's rows s2,s3 (positions freed by prev cb's bar2);
        //     kh0 reads positions 0,1 (staged >=1 barrier ago) — disjoint.
        if (cb > 0) {
            stage1(x, &Xs[2 * 8320], b, cb, h0 + 1, t);
            stage1(x, &Xs[3 * 8320], b, cb, h0 + 2, t);
        }
        COMPUTE_KH(0);
        __syncthreads();

        // I1: stage (cb+1).s0 into pos0 (freed by bar0); kh1 reads 1,2.
        if (cb < 3) stage1(x, &Xs[0 * 8320], b, cb + 1, h0 - 1, t);
        COMPUTE_KH(1);
        __syncthreads();

        // I2: stage (cb+1).s1 into pos1 (freed by bar1); kh2 reads 2,3.
        if (cb < 3) stage1(x, &Xs[1 * 8320], b, cb + 1, h0 + 0, t);
        COMPUTE_KH(2);
        __syncthreads();
    }
#undef COMPUTE_KH

    // ---- epilogue: (acc + bias) * active ----
    #pragma unroll
    for (int i = 0; i < 4; ++i) {
        const int m0 = mhalf * 64 + (i << 4) + (q << 2);
        const f32x4 bv = *(const f32x4*)(bias + m0);
        #pragma unroll
        for (int j = 0; j < 8; ++j) {
            const int w = (j << 4) + l16;
            const float a = act[(g << 7) + w];
            float* base = out + (((b << 7) + m0) << 14) + ((h0 + g) << 7) + w;
            #pragma unroll
            for (int rg = 0; rg < 4; ++rg)
                base[rg << 14] = (acc[i][j][rg] + bv[rg]) * a;
        }
    }
}

// ---------------- fallback (used only if ws too small) ----------------
#define LDAF 40
__global__ __launch_bounds__(256, 2)
void myconv_fb(const float* __restrict__ x,
               const int* __restrict__ mask,
               const float* __restrict__ wgt,
               const float* __restrict__ bias,
               float* __restrict__ out)
{
    __shared__ unsigned short As[128 * LDAF];
    __shared__ unsigned short Bs[128 * LDAF];
    __shared__ float act[128];

    const int t   = threadIdx.x;
    const int blk = blockIdx.x;
    const int b   = blk >> 7;
    const int h   = blk & 127;

    if (t < 128) {
        int any = 0;
        #pragma unroll
        for (int kh = 0; kh < 3; ++kh) {
            int hh = h + kh - 1;
            if ((unsigned)hh < 128u) {
                const int* mrow = mask + (b * 128 + hh) * 128;
                #pragma unroll
                for (int kw = 0; kw < 3; ++kw) {
                    int ww = t + kw - 1;
                    if ((unsigned)ww < 128u) any |= mrow[ww];
                }
            }
        }
        act[t] = any ? 1.0f : 0.0f;
    }

    const int lane = t & 63;
    const int l16  = lane & 15;
    const int half = lane >> 4;
    const int wv   = t >> 6;
    const int wm   = (wv >> 1) << 6;
    const int wn   = (wv & 1) << 6;

    f32x4 acc[4][4];
    const f32x4 fzero = {0.f, 0.f, 0.f, 0.f};
    #pragma unroll
    for (int i = 0; i < 4; ++i)
        #pragma unroll
        for (int j = 0; j < 4; ++j)
            acc[i][j] = fzero;

    const int am  = t >> 3;
    const int ac4 = (t & 7) << 2;
    const int n     = t & 127;
    const int khalf = __builtin_amdgcn_readfirstlane(t >> 7);
    const int xb    = b << 21;

    for (int kt = 0; kt < 36; ++kt) {
        __syncthreads();
        #pragma unroll
        for (int jj = 0; jj < 4; ++jj) {
            const int m = am + (jj << 5);
            const float4 v = *(const float4*)(wgt + m * 1152 + kt * 32 + ac4);
            unsigned short* dst = &As[m * LDAF + ac4];
            dst[0] = f2bf(v.x); dst[1] = f2bf(v.y); dst[2] = f2bf(v.z); dst[3] = f2bf(v.w);
        }
        u16x8 bv0, bv1;
        #pragma unroll
        for (int s = 0; s < 16; ++s) {
            const int k  = kt * 32 + khalf * 16 + s;
            const int ci = (k * 7282) >> 16;
            const int r  = k - ci * 9;
            const int kh = (r >= 3) + (r >= 6);
            const int kw = r - kh * 3;
            const int hh = h + kh - 1;
            float v = 0.f;
            if ((unsigned)hh < 128u) {
                const int ww = n + kw - 1;
                if ((unsigned)ww < 128u)
                    v = x[xb + (ci << 14) + (hh << 7) + ww];
            }
            if (s < 8) bv0[s] = f2bf(v); else bv1[s - 8] = f2bf(v);
        }
        *(u16x8*)&Bs[n * LDAF + khalf * 16]     = bv0;
        *(u16x8*)&Bs[n * LDAF + khalf * 16 + 8] = bv1;

        __syncthreads();

        bf16x8 af[4], bfr[4];
        #pragma unroll
        for (int i = 0; i < 4; ++i)
            af[i] = *(const bf16x8*)&As[(wm + (i << 4) + l16) * LDAF + (half << 3)];
        #pragma unroll
        for (int j = 0; j < 4; ++j)
            bfr[j] = *(const bf16x8*)&Bs[(wn + (j << 4) + l16) * LDAF + (half << 3)];
        #pragma unroll
        for (int i = 0; i < 4; ++i)
            #pragma unroll
            for (int j = 0; j < 4; ++j)
                acc[i][j] = __builtin_amdgcn_mfma_f32_16x16x32_bf16(af[i], bfr[j], acc[i][j], 0, 0, 0);
    }

    #pragma unroll
    for (int i = 0; i < 4; ++i) {
        #pragma unroll
        for (int j = 0; j < 4; ++j) {
            const int ncol = wn + (j << 4) + l16;
            const float a  = act[ncol];
            #pragma unroll
            for (int rg = 0; rg < 4; ++rg) {
                const int m = wm + (i << 4) + (half << 2) + rg;
                out[(((b << 7) + m) << 14) + (h << 7) + ncol] =
                    (acc[i][j][rg] + bias[m]) * a;
            }
        }
    }
}

extern "C" void kernel_launch(void* const* d_in, const int* in_sizes, int n_in,
                              void* d_out, int out_size, void* d_ws, size_t ws_size,
                              hipStream_t stream) {
    const float* x    = (const float*)d_in[0];
    const int*   mask = (const int*)d_in[1];
    const float* wgt  = (const float*)d_in[2];
    const float* bias = (const float*)d_in[3];
    float* out        = (float*)d_out;

    const size_t WP_ELEMS = 36ull * 128 * 32;   // 147,456 bf16
    if (ws_size >= WP_ELEMS * 2) {
        unsigned short* wpw = (unsigned short*)d_ws;
        setup_wp<<<dim3(576), dim3(256), 0, stream>>>(wgt, wpw);
        myconv12<<<dim3(512), dim3(256), 0, stream>>>(x, mask, wpw, bias, out);
    } else {
        myconv_fb<<<dim3(1024), dim3(256), 0, stream>>>(x, mask, wgt, bias, out);
    }
}